// Round 15
// baseline (878.333 us; speedup 1.0000x reference)
//
#include <hip/hip_runtime.h>
#include <math.h>

#define BB 128
#define NN 128
#define KK 16
#define MEDGE (BB*NN*KK)   // 262144 edges
#define MNODE (BB*NN)      // 16384 nodes

typedef __bf16 bf16x8 __attribute__((ext_vector_type(8)));
typedef float  floatx4 __attribute__((ext_vector_type(4)));
typedef unsigned short u16;
typedef u16 ushort8_alias __attribute__((ext_vector_type(8)));

// ---------------------------------------------------------------- utilities

__device__ __forceinline__ unsigned ord32(float f) {
  unsigned u = __float_as_uint(f);
  return (u & 0x80000000u) ? ~u : (u | 0x80000000u);
}

__device__ __forceinline__ unsigned long long shfl_xor_u64(unsigned long long v, int m) {
  unsigned lo = (unsigned)(v & 0xffffffffull);
  unsigned hi = (unsigned)(v >> 32);
  lo = __shfl_xor(lo, m, 64);
  hi = __shfl_xor(hi, m, 64);
  return (((unsigned long long)hi) << 32) | (unsigned long long)lo;
}

__device__ __forceinline__ u16 bf16_rne_bits(float x) {
  unsigned u = __float_as_uint(x);
  return (u16)((u + 0x7FFF + ((u >> 16) & 1)) >> 16);
}

// ---------------------------------------------------------------- fused kNN (dist + select)
template<int C>
__global__ __launch_bounds__(256) void knn_fused(const float* __restrict__ x,
                                                 int* __restrict__ idx) {
  constexpr int S = C + 2;
  constexpr int DS = NN + 2;
  constexpr int XSZ = (NN * S > 64 * DS) ? NN * S : 64 * DS;   // union sizing
  __shared__ float xs[XSZ];   // x staging, then reused as Dl[64 * DS]
  __shared__ float sq[NN];
  int b = blockIdx.x >> 1, half = blockIdx.x & 1;
  const float* xb = x + (size_t)b * NN * C;
  int tid = threadIdx.x;

  for (int t = tid; t < NN * C; t += 256) {
    int row = t / C, c = t - row * C;
    xs[row * S + c] = xb[t];
  }
  __syncthreads();
  if (tid < NN) {
    const float* xr = xs + tid * S;
    float s = 0.f;
    for (int c = 0; c < C; ++c) s = fmaf(xr[c], xr[c], s);
    sq[tid] = s;
  }
  __syncthreads();

  int rg = tid >> 5, cg = tid & 31;
  int r0 = half * 64 + rg * 8;
  float acc[8][4];
#pragma unroll
  for (int i = 0; i < 8; ++i)
#pragma unroll
    for (int j = 0; j < 4; ++j) acc[i][j] = 0.f;
  for (int c = 0; c < C; c += 2) {
    float2 av[8], bv[4];
#pragma unroll
    for (int i = 0; i < 8; ++i) av[i] = *(const float2*)&xs[(r0 + i) * S + c];
#pragma unroll
    for (int j = 0; j < 4; ++j) bv[j] = *(const float2*)&xs[(cg + 32 * j) * S + c];
#pragma unroll
    for (int i = 0; i < 8; ++i)
#pragma unroll
      for (int j = 0; j < 4; ++j) {
        acc[i][j] = fmaf(av[i].x, bv[j].x, acc[i][j]);
        acc[i][j] = fmaf(av[i].y, bv[j].y, acc[i][j]);
      }
  }
  float dv[8][4];
#pragma unroll
  for (int i = 0; i < 8; ++i) {
    float sn = sq[r0 + i];
#pragma unroll
    for (int j = 0; j < 4; ++j) dv[i][j] = sn - 2.f * acc[i][j] + sq[cg + 32 * j];
  }
  __syncthreads();
  float* Dl = xs;
#pragma unroll
  for (int i = 0; i < 8; ++i)
#pragma unroll
    for (int j = 0; j < 4; ++j)
      Dl[(rg * 8 + i) * DS + (cg + 32 * j)] = dv[i][j];
  __syncthreads();

  int lane = tid & 63, wv = tid >> 6;
  for (int t = 0; t < 16; ++t) {
    int lr = wv * 16 + t;
    int nd = b * NN + half * 64 + lr;
    unsigned long long key[2];
    key[0] = (((unsigned long long)ord32(Dl[lr * DS + lane])) << 32) | (unsigned)lane;
    key[1] = (((unsigned long long)ord32(Dl[lr * DS + lane + 64])) << 32) | (unsigned)(lane + 64);
    int* out = idx + (size_t)nd * KK;
    for (int r = 0; r < KK; ++r) {
      unsigned long long mk = key[0] < key[1] ? key[0] : key[1];
#pragma unroll
      for (int off = 32; off > 0; off >>= 1) {
        unsigned long long o = shfl_xor_u64(mk, off);
        if (o < mk) mk = o;
      }
      int wm = (int)(mk & 0xffffffffu);
      if (lane == 0) out[r] = wm;
      if ((wm & 63) == lane) key[wm >> 6] = ~0ull;
    }
  }
}

// ---------------------------------------------------------------- node GEMM (scalar, layer-1 only)
__global__ __launch_bounds__(256) void node_gemm(const float* __restrict__ x,
                                                 const float* __restrict__ W,
                                                 float* __restrict__ p, float* __restrict__ q,
                                                 int Cin, int Cout) {
  int c = threadIdx.x;
  __shared__ float xr[128];
  for (int r = 0; r < 8; ++r) {
    int row = blockIdx.x * 8 + r;
    __syncthreads();
    for (int i = c; i < Cin; i += blockDim.x) xr[i] = x[(size_t)row * Cin + i];
    __syncthreads();
    float a = 0.f, qv = 0.f;
    for (int i = 0; i < Cin; ++i) {
      float xv = xr[i];
      a  = fmaf(xv, W[i * Cout + c], a);
      qv = fmaf(xv, W[(Cin + i) * Cout + c], qv);
    }
    p[(size_t)row * Cout + c] = a - qv;
    q[(size_t)row * Cout + c] = qv;
  }
}

// ---------------------------------------------------------------- W1 packing (16x16x32 layout)
template<int K, int N>
__global__ __launch_bounds__(256) void pack_w1_16(const float* __restrict__ W1,
                                                  u16* __restrict__ Wh, u16* __restrict__ Wl) {
  int t = blockIdx.x * 256 + threadIdx.x;
  if (t >= K * N) return;
  constexpr int C = N / 2;
  constexpr int NT = N / 16;
  int j = t & 7, lane = (t >> 3) & 63, tile = t >> 9;
  int nt = tile % NT, kt = tile / NT;
  int row = kt * 32 + (lane >> 4) * 8 + j;
  int col = nt * 16 + (lane & 15);
  float w;
  if (col < C) w = W1[row * C + col] - W1[(K + row) * C + col];
  else         w = W1[(K + row) * C + (col - C)];
  u16 h = bf16_rne_bits(w);
  float hf = __uint_as_float(((unsigned)h) << 16);
  Wh[t] = h;
  Wl[t] = bf16_rne_bits(w - hf);
}

// ---------------------------------------------------------------- node GEMM v2 (v9-style)
template<int K, int N>
__global__ __launch_bounds__(512, 4) void node_gemm_v2(
    const float* __restrict__ x, const u16* __restrict__ Wh, const u16* __restrict__ Wl,
    float* __restrict__ p, float* __restrict__ q) {
  constexpr int C = N / 2;
  constexpr int KT = K / 32;
  constexpr int NT = N / 16;
  constexpr int NCOL = 64, NTS = 4;
  constexpr int NSLICE = N / 64;
  constexpr int CCH = KT * NTS * 2 * 64;
  __shared__ __align__(16) u16 Bst[CCH * 8];

  int tid = threadIdx.x, lane = tid & 63, wv = tid >> 6;
  int r = lane & 15, kseg = lane >> 4;
  int g = blockIdx.x / NSLICE, slice = blockIdx.x % NSLICE;
  int rowBase = g * 128 + wv * 16;
  const float* xr = x + (size_t)(rowBase + r) * K;

  for (int i = tid; i < CCH; i += 512) {
    int c = i & 63, h = (i >> 6) & 1, rest = i >> 7;
    int nt = rest % NTS, kt = rest / NTS;
    const ushort8_alias* src = h ? (const ushort8_alias*)Wl : (const ushort8_alias*)Wh;
    ((ushort8_alias*)Bst)[i] = src[((size_t)kt * NT + slice * NTS + nt) * 64 + c];
  }
  __syncthreads();

  floatx4 acc[NTS];
#pragma unroll
  for (int nt = 0; nt < NTS; ++nt) acc[nt] = {0.f, 0.f, 0.f, 0.f};

#pragma unroll
  for (int kt = 0; kt < KT; ++kt) {
    int c0 = kt * 32 + kseg * 8;
    float4 xa = *(const float4*)(xr + c0);
    float4 xb = *(const float4*)(xr + c0 + 4);
    float hv[8] = {xa.x, xa.y, xa.z, xa.w, xb.x, xb.y, xb.z, xb.w};
    bf16x8 ah, al;
#pragma unroll
    for (int t = 0; t < 8; ++t) {
      __bf16 hb = (__bf16)hv[t];
      ah[t] = hb;
      al[t] = (__bf16)(hv[t] - (float)hb);
    }
#pragma unroll
    for (int nt = 0; nt < NTS; ++nt) {
      int base = (kt * NTS + nt) * 128 + lane;
      bf16x8 bh = __builtin_bit_cast(bf16x8, ((const ushort8_alias*)Bst)[base]);
      bf16x8 bl = __builtin_bit_cast(bf16x8, ((const ushort8_alias*)Bst)[base + 64]);
      acc[nt] = __builtin_amdgcn_mfma_f32_16x16x32_bf16(ah, bh, acc[nt], 0, 0, 0);
      acc[nt] = __builtin_amdgcn_mfma_f32_16x16x32_bf16(al, bh, acc[nt], 0, 0, 0);
      acc[nt] = __builtin_amdgcn_mfma_f32_16x16x32_bf16(ah, bl, acc[nt], 0, 0, 0);
    }
  }

#pragma unroll
  for (int nt = 0; nt < NTS; ++nt) {
    int n = slice * NCOL + nt * 16 + r;
    float* dst = (n < C) ? p : q;
    int col = (n < C) ? n : n - C;
#pragma unroll
    for (int gi = 0; gi < 4; ++gi) {
      int row = rowBase + kseg * 4 + gi;
      dst[(size_t)row * C + col] = acc[nt][gi];
    }
  }
}

// ---------------------------------------------------------------- BN1 stats (banked atomics)
template<int C>
__global__ __launch_bounds__(256) void edge_stats1v(const float* __restrict__ p,
                                                    const float* __restrict__ q,
                                                    const float* __restrict__ b1,
                                                    const int* __restrict__ idx,
                                                    float* __restrict__ statsL) {
  constexpr int G = C / 4;
  constexpr int KL = 64 / G;
  int tid = threadIdx.x, lane = tid & 63, wv = tid >> 6;
  int nd = blockIdx.x * 4 + wv;
  int b = nd >> 7;
  int g = lane % G, kl = lane / G;
  int bank = blockIdx.x & 7;

  __shared__ float sS[C], sSS[C];
  if (tid < C) { sS[tid] = 0.f; sSS[tid] = 0.f; }
  __syncthreads();

  const float* pr = p + (size_t)nd * C;
  float4 pv = *(const float4*)(pr + g * 4);
  float4 bv = *(const float4*)(b1 + g * 4);
  pv.x += bv.x; pv.y += bv.y; pv.z += bv.z; pv.w += bv.w;
  float4 s = {0, 0, 0, 0}, ss = {0, 0, 0, 0};
  const int* id = idx + (size_t)nd * KK;
#pragma unroll
  for (int k0 = 0; k0 < KK; k0 += KL) {
    int j = id[k0 + kl];
    float4 q4 = *(const float4*)(q + (size_t)(b * NN + j) * C + g * 4);
    float y;
    y = pv.x + q4.x; s.x += y; ss.x = fmaf(y, y, ss.x);
    y = pv.y + q4.y; s.y += y; ss.y = fmaf(y, y, ss.y);
    y = pv.z + q4.z; s.z += y; ss.z = fmaf(y, y, ss.z);
    y = pv.w + q4.w; s.w += y; ss.w = fmaf(y, y, ss.w);
  }
#pragma unroll
  for (int off = G; off < 64; off <<= 1) {
    s.x += __shfl_xor(s.x, off); ss.x += __shfl_xor(ss.x, off);
    s.y += __shfl_xor(s.y, off); ss.y += __shfl_xor(ss.y, off);
    s.z += __shfl_xor(s.z, off); ss.z += __shfl_xor(ss.z, off);
    s.w += __shfl_xor(s.w, off); ss.w += __shfl_xor(ss.w, off);
  }
  if (kl == 0) {
    atomicAdd(&sS[g * 4 + 0], s.x); atomicAdd(&sSS[g * 4 + 0], ss.x);
    atomicAdd(&sS[g * 4 + 1], s.y); atomicAdd(&sSS[g * 4 + 1], ss.y);
    atomicAdd(&sS[g * 4 + 2], s.z); atomicAdd(&sSS[g * 4 + 2], ss.z);
    atomicAdd(&sS[g * 4 + 3], s.w); atomicAdd(&sSS[g * 4 + 3], ss.w);
  }
  __syncthreads();
  if (tid < C) {
    atomicAdd(&statsL[bank * 256 + tid], sS[tid]);
    atomicAdd(&statsL[2048 + bank * 256 + tid], sSS[tid]);
  }
}

// ---------------------------------------------------------------- BN1 apply (in-place p/q transform)
// p <- (p + b1)*scl + shf ; q <- q*scl. Then relu(p'+q') == BN1+ReLU of the edge.
template<int C>
__global__ __launch_bounds__(256) void bn1_apply(float* __restrict__ p, float* __restrict__ q,
                                                 const float* __restrict__ statsL,
                                                 const float* __restrict__ g1,
                                                 const float* __restrict__ e1,
                                                 const float* __restrict__ b1) {
  __shared__ float scl[C], shf[C];
  int tid = threadIdx.x;
  if (tid < C) {
    float s = 0.f, ss = 0.f;
#pragma unroll
    for (int k = 0; k < 8; ++k) {
      s += statsL[k * 256 + tid];
      ss += statsL[2048 + k * 256 + tid];
    }
    float mean = s / (float)MEDGE;
    float var = ss / (float)MEDGE - mean * mean;
    if (var < 0.f) var = 0.f;
    float sc = g1[tid] * rsqrtf(var + 1e-5f);
    scl[tid] = sc;
    shf[tid] = e1[tid] - mean * sc + sc * b1[tid];
  }
  __syncthreads();
  size_t i4 = (size_t)blockIdx.x * 256 + tid;
  int c0 = (int)((i4 * 4) & (C - 1));
  float4 sv = *(const float4*)(scl + c0);
  float4 tv = *(const float4*)(shf + c0);
  float4 pv = ((const float4*)p)[i4];
  pv.x = fmaf(pv.x, sv.x, tv.x); pv.y = fmaf(pv.y, sv.y, tv.y);
  pv.z = fmaf(pv.z, sv.z, tv.z); pv.w = fmaf(pv.w, sv.w, tv.w);
  ((float4*)p)[i4] = pv;
  float4 qv = ((const float4*)q)[i4];
  qv.x *= sv.x; qv.y *= sv.y; qv.z *= sv.z; qv.w *= sv.w;
  ((float4*)q)[i4] = qv;
}

// ---------------------------------------------------------------- W2 packing (16x16x32)
template<int C>
__global__ __launch_bounds__(256) void pack_w2(const float* __restrict__ W,
                                               u16* __restrict__ Wh, u16* __restrict__ Wl) {
  int t = blockIdx.x * 256 + threadIdx.x;
  if (t >= C * C) return;
  constexpr int NT = C / 16;
  int j = t & 7, lane = (t >> 3) & 63, tile = t >> 9;
  int nt = tile % NT, kt = tile / NT;
  int row = kt * 32 + (lane >> 4) * 8 + j;
  int col = nt * 16 + (lane & 15);
  float w = W[row * C + col];
  u16 h = bf16_rne_bits(w);
  float hf = __uint_as_float(((unsigned)h) << 16);
  Wh[t] = h;
  Wl[t] = bf16_rne_bits(w - hf);
}

// ---------------------------------------------------------------- MFMA edge GEMM2 v11
// 1024 threads = 16 waves = 16 nodes/block x one N-slice. B window in LDS
// shared by 16 waves (staging amortized 2x vs v10); p/q pre-transformed by
// bn1_apply so A-build is just relu(p'+q') + hi/lo split. C<=128: NSLICE=1
// (no gather duplication) and a single barrier; C=256: 2 windows.
template<int C, int NCOL, int CK>
__global__ __launch_bounds__(1024, 8) void edge_gemm2_v11(
    const float* __restrict__ p, const float* __restrict__ q,
    const int* __restrict__ idx,
    const u16* __restrict__ Wh, const u16* __restrict__ Wl,
    const float* __restrict__ b2,
    float* __restrict__ zmax, float* __restrict__ zmin,
    float* __restrict__ s2b, float* __restrict__ ss2b) {
  constexpr int KT = C / 32;
  constexpr int NT = C / 16;
  constexpr int NSLICE = C / NCOL;
  constexpr int NTS = NCOL / 16;
  constexpr int NWIN = KT / CK;
  constexpr int CCH = CK * NTS * 2 * 64;
  __shared__ __align__(16) u16 Bst[CCH * 8];
  __shared__ float sS[NCOL], sSS[NCOL];

  int tid = threadIdx.x, lane = tid & 63, wv = tid >> 6;
  int r = lane & 15, kseg = lane >> 4;

  int g = blockIdx.x / NSLICE, slice = blockIdx.x % NSLICE;
  // XCD swizzle: 8 groups (of 16 nodes) per batch; same-batch groups share an XCD.
  int u = g >> 3, xcd = g & 7;
  int b = xcd + 8 * (u >> 3);
  int nodeBase = b * NN + (u & 7) * 16;
  int nd = nodeBase + wv;

  if (tid < NCOL) { sS[tid] = 0.f; sSS[tid] = 0.f; }

  int j = idx[(size_t)nd * KK + r];
  const float* pr = p + (size_t)nd * C;
  const float* qr = q + (size_t)(b * NN + j) * C;

  floatx4 acc[NTS];
#pragma unroll
  for (int nt = 0; nt < NTS; ++nt) {
    float bv = b2[slice * NCOL + nt * 16 + r];
    acc[nt] = {bv, bv, bv, bv};
  }

#pragma unroll
  for (int w = 0; w < NWIN; ++w) {
    if (w > 0) __syncthreads();
    for (int i = tid; i < CCH; i += 1024) {
      int c = i & 63, h = (i >> 6) & 1, rest = i >> 7;
      int nt = rest % NTS, kk = rest / NTS;
      const ushort8_alias* src = h ? (const ushort8_alias*)Wl : (const ushort8_alias*)Wh;
      ((ushort8_alias*)Bst)[i] = src[((size_t)(w * CK + kk) * NT + slice * NTS + nt) * 64 + c];
    }
    __syncthreads();

#pragma unroll
    for (int kk = 0; kk < CK; ++kk) {
      int c0 = (w * CK + kk) * 32 + kseg * 8;
      float4 pa = *(const float4*)(pr + c0);
      float4 pb = *(const float4*)(pr + c0 + 4);
      float4 qa = *(const float4*)(qr + c0);
      float4 qb = *(const float4*)(qr + c0 + 4);
      float hv[8];
      hv[0] = fmaxf(pa.x + qa.x, 0.f);
      hv[1] = fmaxf(pa.y + qa.y, 0.f);
      hv[2] = fmaxf(pa.z + qa.z, 0.f);
      hv[3] = fmaxf(pa.w + qa.w, 0.f);
      hv[4] = fmaxf(pb.x + qb.x, 0.f);
      hv[5] = fmaxf(pb.y + qb.y, 0.f);
      hv[6] = fmaxf(pb.z + qb.z, 0.f);
      hv[7] = fmaxf(pb.w + qb.w, 0.f);
      bf16x8 ah, al;
#pragma unroll
      for (int t = 0; t < 8; ++t) {
        __bf16 hb = (__bf16)hv[t];
        ah[t] = hb;
        al[t] = (__bf16)(hv[t] - (float)hb);
      }
#pragma unroll
      for (int nt = 0; nt < NTS; ++nt) {
        int base = (kk * NTS + nt) * 128 + lane;
        bf16x8 bh = __builtin_bit_cast(bf16x8, ((const ushort8_alias*)Bst)[base]);
        bf16x8 bl = __builtin_bit_cast(bf16x8, ((const ushort8_alias*)Bst)[base + 64]);
        acc[nt] = __builtin_amdgcn_mfma_f32_16x16x32_bf16(ah, bh, acc[nt], 0, 0, 0);
        acc[nt] = __builtin_amdgcn_mfma_f32_16x16x32_bf16(al, bh, acc[nt], 0, 0, 0);
        acc[nt] = __builtin_amdgcn_mfma_f32_16x16x32_bf16(ah, bl, acc[nt], 0, 0, 0);
      }
    }
  }

  // epilogue: C/D col = lane&15, row (neighbor) = kseg*4+reg
  __syncthreads();
  int bank = blockIdx.x & 7;
#pragma unroll
  for (int nt = 0; nt < NTS; ++nt) {
    float s = 0.f, ss = 0.f, mx = -INFINITY, mn = INFINITY;
#pragma unroll
    for (int gi = 0; gi < 4; ++gi) {
      float z = acc[nt][gi];
      s += z; ss = fmaf(z, z, ss);
      mx = fmaxf(mx, z); mn = fminf(mn, z);
    }
    mx = fmaxf(mx, __shfl_xor(mx, 16)); mn = fminf(mn, __shfl_xor(mn, 16));
    s += __shfl_xor(s, 16); ss += __shfl_xor(ss, 16);
    mx = fmaxf(mx, __shfl_xor(mx, 32)); mn = fminf(mn, __shfl_xor(mn, 32));
    s += __shfl_xor(s, 32); ss += __shfl_xor(ss, 32);
    if (kseg == 0) {
      int colL = nt * 16 + r;
      int col = slice * NCOL + colL;
      zmax[(size_t)nd * C + col] = mx;
      zmin[(size_t)nd * C + col] = mn;
      atomicAdd(&sS[colL], s);
      atomicAdd(&sSS[colL], ss);
    }
  }
  __syncthreads();
  if (tid < NCOL) {
    atomicAdd(&s2b[bank * 256 + slice * NCOL + tid], sS[tid]);
    atomicAdd(&ss2b[bank * 256 + slice * NCOL + tid], sSS[tid]);
  }
}

// ---------------------------------------------------------------- finalize (banked BN2 params)
__global__ __launch_bounds__(256) void finalize2_kernel(const float* __restrict__ zmax,
                                                        const float* __restrict__ zmin,
                                                        const float* __restrict__ s2b,
                                                        const float* __restrict__ ss2b,
                                                        const float* __restrict__ g2,
                                                        const float* __restrict__ e2,
                                                        float* __restrict__ out, int Cmask) {
  int t = blockIdx.x * 256 + threadIdx.x;
  int c = t & Cmask;
  float s = 0.f, ss = 0.f;
#pragma unroll
  for (int k = 0; k < 8; ++k) {
    s += s2b[k * 256 + c];
    ss += ss2b[k * 256 + c];
  }
  float mean = s / (float)MEDGE;
  float var = ss / (float)MEDGE - mean * mean;
  if (var < 0.f) var = 0.f;
  float scl = g2[c] * rsqrtf(var + 1e-5f);
  float shf = e2[c] - mean * scl;
  float v = (scl >= 0.f) ? zmax[t] : zmin[t];
  out[t] = fmaxf(fmaf(v, scl, shf), 0.f);
}

// ---------------------------------------------------------------- pooling
__global__ __launch_bounds__(256) void pool_kernel(const float* __restrict__ h,
                                                   float* __restrict__ pooled) {
  int b = blockIdx.x, c = threadIdx.x;
  float s = 0.f, mx = -INFINITY;
  for (int n = 0; n < NN; ++n) {
    float v = h[(size_t)(b * NN + n) * 256 + c];
    s += v;
    mx = fmaxf(mx, v);
  }
  pooled[b * 512 + c] = s * (1.f / 128.f);
  pooled[b * 512 + 256 + c] = mx;
}

// ---------------------------------------------------------------- FC tail
__global__ __launch_bounds__(256) void fc1_fused(const float* __restrict__ pooled,
                                                 const float* __restrict__ W,
                                                 const float* __restrict__ bias,
                                                 float* __restrict__ t1raw,
                                                 float* __restrict__ fs, float* __restrict__ fss) {
  int b = blockIdx.x, c = threadIdx.x;
  __shared__ float row[512];
  row[c] = pooled[b * 512 + c];
  row[c + 256] = pooled[b * 512 + 256 + c];
  __syncthreads();
  float acc = bias[c];
  for (int i = 0; i < 512; ++i) acc = fmaf(row[i], W[i * 256 + c], acc);
  t1raw[b * 256 + c] = acc;
  atomicAdd(&fs[c], acc);
  atomicAdd(&fss[c], acc * acc);
}

__global__ __launch_bounds__(256) void fc2_fused(const float* __restrict__ t1raw,
                                                 const float* __restrict__ fs,
                                                 const float* __restrict__ fss,
                                                 const float* __restrict__ g1,
                                                 const float* __restrict__ e1,
                                                 const float* __restrict__ W,
                                                 const float* __restrict__ bias,
                                                 float* __restrict__ t2raw,
                                                 float* __restrict__ gs, float* __restrict__ gss) {
  int b = blockIdx.x, c = threadIdx.x;
  __shared__ float row[256];
  {
    float mean = fs[c] / 128.f;
    float var = fss[c] / 128.f - mean * mean;
    if (var < 0.f) var = 0.f;
    float scl = g1[c] * rsqrtf(var + 1e-5f);
    float shf = e1[c] - mean * scl;
    row[c] = fmaxf(fmaf(t1raw[b * 256 + c], scl, shf), 0.f);
  }
  __syncthreads();
  if (c < 128) {
    float acc = bias[c];
    for (int i = 0; i < 256; ++i) acc = fmaf(row[i], W[i * 128 + c], acc);
    t2raw[b * 128 + c] = acc;
    atomicAdd(&gs[c], acc);
    atomicAdd(&gss[c], acc * acc);
  }
}

__global__ __launch_bounds__(256) void fc3_fused(const float* __restrict__ t2raw,
                                                 const float* __restrict__ gs,
                                                 const float* __restrict__ gss,
                                                 const float* __restrict__ g2,
                                                 const float* __restrict__ e2,
                                                 const float* __restrict__ W,
                                                 const float* __restrict__ bias,
                                                 float* __restrict__ out) {
  __shared__ float row[128 * 2];
  int t = threadIdx.x;
  if (t < 128) {
    float mean = gs[t] / 128.f;
    float var = gss[t] / 128.f - mean * mean;
    if (var < 0.f) var = 0.f;
    float scl = g2[t] * rsqrtf(var + 1e-5f);
    row[t] = scl;
    row[128 + t] = e2[t] - mean * scl;
  }
  __syncthreads();
  int b = t >> 1, jj = t & 1;
  float acc = bias[jj];
  for (int r = 0; r < 128; ++r) {
    float v = fmaxf(fmaf(t2raw[b * 128 + r], row[r], row[128 + r]), 0.f);
    acc = fmaf(v, W[r * 2 + jj], acc);
  }
  out[t] = acc;
}

// ---------------------------------------------------------------- per-layer driver

struct LayerPtrs {
  int* idx; float *p, *q, *zmx, *zmn;
  u16 *Wh, *Wl, *Wh1, *Wl1;
};

template<int Cin, int C>
static void run_edgeconv(const float* xin,
                         const float* W1, const float* b1, const float* g1, const float* e1,
                         const float* W2, const float* b2, const float* g2, const float* e2,
                         float* hout, float* statsL, const LayerPtrs& L, hipStream_t stream) {
  float* s2b = statsL + 4096;
  float* ss2b = statsL + 6144;

  knn_fused<Cin><<<dim3(BB * 2), dim3(256), 0, stream>>>(xin, L.idx);
  if constexpr (Cin >= 16) {
    pack_w1_16<Cin, 2 * C><<<dim3((Cin * 2 * C + 255) / 256), dim3(256), 0, stream>>>(W1, L.Wh1, L.Wl1);
    constexpr int NSL1 = (2 * C) / 64;
    node_gemm_v2<Cin, 2 * C><<<dim3((MNODE / 128) * NSL1), dim3(512), 0, stream>>>(
        xin, L.Wh1, L.Wl1, L.p, L.q);
  } else {
    node_gemm<<<dim3(MNODE / 8), dim3(C), 0, stream>>>(xin, W1, L.p, L.q, Cin, C);
  }
  pack_w2<C><<<dim3((C * C + 255) / 256), dim3(256), 0, stream>>>(W2, L.Wh, L.Wl);
  edge_stats1v<C><<<dim3(MNODE / 4), dim3(256), 0, stream>>>(L.p, L.q, b1, L.idx, statsL);
  bn1_apply<C><<<dim3(MNODE * C / 1024), dim3(256), 0, stream>>>(L.p, L.q, statsL, g1, e1, b1);
  constexpr int NCOL = (C == 64) ? 64 : 128;
  constexpr int CKW = (C == 64) ? 2 : 4;
  constexpr int NSL = C / NCOL;
  edge_gemm2_v11<C, NCOL, CKW><<<dim3((MNODE / 16) * NSL), dim3(1024), 0, stream>>>(
      L.p, L.q, L.idx, L.Wh, L.Wl, b2, L.zmx, L.zmn, s2b, ss2b);
  finalize2_kernel<<<dim3(MNODE * C / 256), dim3(256), 0, stream>>>(
      L.zmx, L.zmn, s2b, ss2b, g2, e2, hout, C - 1);
}

// ---------------------------------------------------------------- launch

extern "C" void kernel_launch(void* const* d_in, const int* in_sizes, int n_in,
                              void* d_out, int out_size, void* d_ws, size_t ws_size,
                              hipStream_t stream) {
  const float* x   = (const float*)d_in[0];
  const float* w11 = (const float*)d_in[1];
  const float* b11 = (const float*)d_in[2];
  const float* g11 = (const float*)d_in[3];
  const float* e11 = (const float*)d_in[4];
  const float* w12 = (const float*)d_in[5];
  const float* b12 = (const float*)d_in[6];
  const float* g12 = (const float*)d_in[7];
  const float* e12 = (const float*)d_in[8];
  const float* w21 = (const float*)d_in[9];
  const float* b21 = (const float*)d_in[10];
  const float* g21 = (const float*)d_in[11];
  const float* e21 = (const float*)d_in[12];
  const float* w22 = (const float*)d_in[13];
  const float* b22 = (const float*)d_in[14];
  const float* g22 = (const float*)d_in[15];
  const float* e22 = (const float*)d_in[16];
  const float* w31 = (const float*)d_in[17];
  const float* b31 = (const float*)d_in[18];
  const float* g31 = (const float*)d_in[19];
  const float* e31 = (const float*)d_in[20];
  const float* w32 = (const float*)d_in[21];
  const float* b32 = (const float*)d_in[22];
  const float* g32 = (const float*)d_in[23];
  const float* e32 = (const float*)d_in[24];
  const float* fw1 = (const float*)d_in[25];
  const float* fb1 = (const float*)d_in[26];
  const float* fg1 = (const float*)d_in[27];
  const float* fe1 = (const float*)d_in[28];
  const float* fw2 = (const float*)d_in[29];
  const float* fb2 = (const float*)d_in[30];
  const float* fg2 = (const float*)d_in[31];
  const float* fe2 = (const float*)d_in[32];
  const float* fw3 = (const float*)d_in[33];
  const float* fb3 = (const float*)d_in[34];

  char* wsb = (char*)d_ws;
  size_t o = 0;
  auto alloc = [&](size_t bytes) -> void* {
    void* r = wsb + o;
    o += (bytes + 255) & ~(size_t)255;
    return r;
  };
  LayerPtrs L;
  L.idx   = (int*)  alloc((size_t)MNODE * KK * sizeof(int));
  L.p     = (float*)alloc((size_t)MNODE * 256 * sizeof(float));
  L.q     = (float*)alloc((size_t)MNODE * 256 * sizeof(float));
  L.zmx   = (float*)alloc((size_t)MNODE * 256 * sizeof(float));
  L.zmn   = (float*)alloc((size_t)MNODE * 256 * sizeof(float));
  L.Wh    = (u16*)  alloc((size_t)256 * 256 * sizeof(u16));
  L.Wl    = (u16*)  alloc((size_t)256 * 256 * sizeof(u16));
  L.Wh1   = (u16*)  alloc((size_t)128 * 512 * sizeof(u16));
  L.Wl1   = (u16*)  alloc((size_t)128 * 512 * sizeof(u16));
  float* statsAll = (float*)alloc((3 * 8192 + 1024) * sizeof(float));
  float* h1buf   = (float*)alloc((size_t)MNODE * 64 * sizeof(float));
  float* h2buf   = (float*)alloc((size_t)MNODE * 128 * sizeof(float));
  float* h3buf   = (float*)alloc((size_t)MNODE * 256 * sizeof(float));
  float* pooled  = (float*)alloc(128 * 512 * sizeof(float));
  float* t1raw   = (float*)alloc(128 * 256 * sizeof(float));
  float* t2raw   = (float*)alloc(128 * 128 * sizeof(float));

  float* fcstats = statsAll + 3 * 8192;
  float* fs  = fcstats;
  float* fss = fcstats + 256;
  float* gs  = fcstats + 512;
  float* gss = fcstats + 768;

  (void)hipMemsetAsync(statsAll, 0, (3 * 8192 + 1024) * sizeof(float), stream);

  run_edgeconv<6,   64 >(x,     w11, b11, g11, e11, w12, b12, g12, e12, h1buf,
                         statsAll, L, stream);
  run_edgeconv<64,  128>(h1buf, w21, b21, g21, e21, w22, b22, g22, e22, h2buf,
                         statsAll + 8192, L, stream);
  run_edgeconv<128, 256>(h2buf, w31, b31, g31, e31, w32, b32, g32, e32, h3buf,
                         statsAll + 16384, L, stream);

  pool_kernel<<<dim3(BB), dim3(256), 0, stream>>>(h3buf, pooled);
  fc1_fused<<<dim3(BB), dim3(256), 0, stream>>>(pooled, fw1, fb1, t1raw, fs, fss);
  fc2_fused<<<dim3(BB), dim3(256), 0, stream>>>(t1raw, fs, fss, fg1, fe1, fw2, fb2, t2raw, gs, gss);
  fc3_fused<<<dim3(1), dim3(256), 0, stream>>>(t2raw, gs, gss, fg2, fe2, fw3, fb3, (float*)d_out);
}